// Round 8
// baseline (155.620 us; speedup 1.0000x reference)
//
#include <hip/hip_runtime.h>
#include <hip/hip_bf16.h>

typedef __bf16 bf16_t;
typedef __attribute__((ext_vector_type(8))) __bf16 bf16x8;
typedef __attribute__((ext_vector_type(4))) __bf16 bf16x4;
typedef __attribute__((ext_vector_type(4))) float f32x4;
typedef __attribute__((ext_vector_type(16))) float f32x16;
typedef __attribute__((ext_vector_type(2))) int i32x2;

#define B_ 2
#define T_ 2048
#define D_ 1024
#define H_ 16
#define DH_ 64
#define RS_ 3072  // fused qkv row stride

static __device__ __forceinline__ f32x4 mfma16(bf16x8 a, bf16x8 b, f32x4 c) {
  return __builtin_amdgcn_mfma_f32_16x16x32_bf16(a, b, c, 0, 0, 0);
}
static __device__ __forceinline__ f32x16 mfma32(bf16x8 a, bf16x8 b, f32x16 c) {
  return __builtin_amdgcn_mfma_f32_32x32x16_bf16(a, b, c, 0, 0, 0);
}
static __device__ __forceinline__ void gld16(const bf16_t* g, bf16_t* l) {
  __builtin_amdgcn_global_load_lds(
      (const __attribute__((address_space(1))) unsigned int*)g,
      (__attribute__((address_space(3))) unsigned int*)l, 16, 0, 0);
}
static __device__ __forceinline__ unsigned lds_addr(const bf16_t* p) {
  return (unsigned)(uintptr_t)(const __attribute__((address_space(3))) bf16_t*)p;
}
static __device__ __forceinline__ i32x2 tr64(unsigned a) {
  i32x2 d;
  asm volatile("ds_read_b64_tr_b16 %0, %1" : "=v"(d) : "v"(a));
  return d;
}
static __device__ __forceinline__ i32x2 tr64o(unsigned a) {  // +128B (4 k-rows)
  i32x2 d;
  asm volatile("ds_read_b64_tr_b16 %0, %1 offset:128" : "=v"(d) : "v"(a));
  return d;
}
static __device__ __forceinline__ unsigned pk2(float lo, float hi2) {
  unsigned short a = __builtin_bit_cast(unsigned short, (bf16_t)lo);
  unsigned short b = __builtin_bit_cast(unsigned short, (bf16_t)hi2);
  return (unsigned)a | ((unsigned)b << 16);
}

#define WAITV4 { asm volatile("s_waitcnt vmcnt(4)" ::: "memory"); __builtin_amdgcn_sched_barrier(0); }
#define WAITV8 { asm volatile("s_waitcnt vmcnt(8)" ::: "memory"); __builtin_amdgcn_sched_barrier(0); }
#define WAITV0 { asm volatile("s_waitcnt vmcnt(0)" ::: "memory"); __builtin_amdgcn_sched_barrier(0); }
#define BAR    { __builtin_amdgcn_s_barrier(); __builtin_amdgcn_sched_barrier(0); }
#define WAITL0 { asm volatile("s_waitcnt lgkmcnt(0)" ::: "memory"); __builtin_amdgcn_sched_barrier(0); }

// ---------------- fp32 -> bf16 conversion ----------------
__global__ __launch_bounds__(256) void cvt_x(const float* __restrict__ in,
                                             bf16_t* __restrict__ out, int n4) {
  int i = blockIdx.x * 256 + threadIdx.x;
  if (i >= n4) return;
  float4 f = reinterpret_cast<const float4*>(in)[i];
  bf16x4 o;
  o[0] = (bf16_t)f.x; o[1] = (bf16_t)f.y; o[2] = (bf16_t)f.z; o[3] = (bf16_t)f.w;
  reinterpret_cast<bf16x4*>(out)[i] = o;
}

__global__ __launch_bounds__(256) void cvt_w4(const float* __restrict__ w0,
                                              const float* __restrict__ w1,
                                              const float* __restrict__ w2,
                                              const float* __restrict__ w3,
                                              bf16_t* __restrict__ out, int n4each) {
  const float* in = blockIdx.y == 0 ? w0 : blockIdx.y == 1 ? w1 : blockIdx.y == 2 ? w2 : w3;
  bf16_t* o = out + (size_t)blockIdx.y * (size_t)n4each * 4;
  int i = blockIdx.x * 256 + threadIdx.x;
  if (i >= n4each) return;
  float4 f = reinterpret_cast<const float4*>(in)[i];
  bf16x4 v;
  v[0] = (bf16_t)f.x; v[1] = (bf16_t)f.y; v[2] = (bf16_t)f.z; v[3] = (bf16_t)f.w;
  reinterpret_cast<bf16x4*>(o)[i] = v;
}

// ---------------- NT GEMM: C = A * B^T (unchanged from R7) ----------------
template <bool STORE_F32, bool QSCALE>
__global__ __launch_bounds__(256) void gemm_nt(const bf16_t* __restrict__ A,
                                               const bf16_t* __restrict__ Bm,
                                               void* __restrict__ Cv,
                                               int M, int N, int K) {
  __shared__ __align__(16) bf16_t As[3][128 * 32];
  __shared__ __align__(16) bf16_t Bs[3][128 * 32];
  const int tid = threadIdx.x, lane = tid & 63, wave = tid >> 6;
  const int l15 = lane & 15;
  const int brow = blockIdx.y * 128, bcol = blockIdx.x * 128;
  const int row0 = (wave >> 1) * 64, col0 = (wave & 1) * 64;
  const float cscale = (QSCALE && bcol < 1024) ? 0.18033688011112042f : 1.0f;

  f32x4 acc[4][4];
#pragma unroll
  for (int m = 0; m < 4; ++m)
#pragma unroll
    for (int n = 0; n < 4; ++n) acc[m][n] = f32x4{0.f, 0.f, 0.f, 0.f};

  const int nst = K >> 5;
  const int srow = tid >> 2;
  const int sc8 = (tid & 3) * 8;
  auto stage = [&](int bi, int ks) {
    const int k0 = ks * 32;
#pragma unroll
    for (int i = 0; i < 2; ++i)
      gld16(A + (size_t)(brow + 64 * i + srow) * K + k0 + sc8,
            &As[bi][2048 * i + 512 * wave]);
#pragma unroll
    for (int i = 0; i < 2; ++i)
      gld16(Bm + (size_t)(bcol + 64 * i + srow) * K + k0 + sc8,
            &Bs[bi][2048 * i + 512 * wave]);
  };

  stage(0, 0);
  stage(1, 1);

#pragma unroll 1
  for (int ks = 0; ks < nst; ++ks) {
    if (ks + 1 < nst) { WAITV4 } else { WAITV0 }
    BAR;
    if (ks + 2 < nst) stage((ks + 2) % 3, ks + 2);

    const bf16_t* Ab = &As[ks % 3][0];
    const bf16_t* Bb = &Bs[ks % 3][0];
    const int ko = (lane >> 4) * 8;
    bf16x8 af[4], bfr[4];
#pragma unroll
    for (int m = 0; m < 4; ++m)
      af[m] = *(const bf16x8*)&Ab[(row0 + 16 * m + l15) * 32 + ko];
#pragma unroll
    for (int n = 0; n < 4; ++n)
      bfr[n] = *(const bf16x8*)&Bb[(col0 + 16 * n + l15) * 32 + ko];
    WAITL0;
#pragma unroll
    for (int m = 0; m < 4; ++m)
#pragma unroll
      for (int n = 0; n < 4; ++n) acc[m][n] = mfma16(af[m], bfr[n], acc[m][n]);
  }

  const int crow = brow + row0 + (lane >> 4) * 4;
  const int ccol = bcol + col0 + l15;
#pragma unroll
  for (int m = 0; m < 4; ++m)
#pragma unroll
    for (int n = 0; n < 4; ++n)
#pragma unroll
      for (int r = 0; r < 4; ++r) {
        size_t idx = (size_t)(crow + 16 * m + r) * N + (ccol + 16 * n);
        float v = acc[m][n][r] * cscale;
        if (STORE_F32) reinterpret_cast<float*>(Cv)[idx] = v;
        else reinterpret_cast<bf16_t*>(Cv)[idx] = (bf16_t)v;
      }
}

// ---------------- causal flash attention ----------------
// Block = 128 thr (2 waves), grid (32 bh, 16 p) -> 512 blocks = 2/CU, 2 waves/SIMD.
//   phase A: wave w owns chunk 2p+w    -> both need exactly p+1 tiles
//   phase B: wave w owns chunk 63-2p-w -> both need exactly 32-p tiles
// Every block stages exactly 33 tiles; no compute guard, zero tail imbalance.
// Triple-buffered K/V, raw s_barrier + counted vmcnt(8): prefetch never drains.
#define CROW(r) ((((r) & 3) + 8 * ((r) >> 2)) + 4 * hi)

__global__ __launch_bounds__(128, 2) void attn_fwd(const bf16_t* __restrict__ qkv,
                                                   bf16_t* __restrict__ ctx) {
  __shared__ __align__(128) bf16_t KV[3][2][64 * 64];  // [buf][K|V][4096] = 48 KB
  const int tid = threadIdx.x;
  const int lane = tid & 63;
  const int wv = tid >> 6;
  const int bh = blockIdx.x, p = blockIdx.y;
  const int b = bh >> 4, h = bh & 15;
  const bf16_t* Qg = qkv + (size_t)b * T_ * RS_ + h * DH_;
  const bf16_t* Kg = Qg + 1024;
  const bf16_t* Vg = Qg + 2048;
  bf16_t* Cg = ctx + (size_t)b * T_ * D_ + h * DH_;

  const int hi = lane >> 5;
  const int l31 = lane & 31;
  const int l15 = lane & 15;

  // cooperative staging: 128 threads cover the 8KB K + 8KB V tile in 4+4 gld16/thread
  auto stage = [&](int bi, int kt) {
    bf16_t* Kb = &KV[bi][0][0];
    bf16_t* Vb = &KV[bi][1][0];
#pragma unroll
    for (int i = 0; i < 4; ++i) {
      int c2 = i * 128 + tid;
      int r = c2 >> 3, g8 = (c2 & 7) ^ (r & 7);
      gld16(Kg + (size_t)(kt * 64 + r) * RS_ + g8 * 8, Kb + i * 1024 + wv * 512);
    }
#pragma unroll
    for (int i = 0; i < 4; ++i) {
      int c2 = i * 128 + tid;
      int pn = c2 >> 7, k = (c2 >> 1) & 63, half = c2 & 1;
      gld16(Vg + (size_t)(kt * 64 + k) * RS_ + pn * 16 + half * 8, Vb + i * 1024 + wv * 512);
    }
  };

#pragma unroll 1
  for (int phase = 0; phase < 2; ++phase) {
    const int c = phase ? (63 - 2 * p - wv) : (2 * p + wv);
    const int q0 = c * 32;
    const int nkt = phase ? (32 - p) : (p + 1);  // identical for both waves

    BAR;  // previous phase's LDS reads fully retired before re-staging
    stage(0, 0);
    stage(1, 1);

    bf16x8 qf[4];
#pragma unroll
    for (int d = 0; d < 4; ++d)
      qf[d] = *(const bf16x8*)&Qg[(size_t)(q0 + l31) * RS_ + d * 16 + hi * 8];

    f32x16 o[2];
#pragma unroll
    for (int n = 0; n < 2; ++n)
#pragma unroll
      for (int r = 0; r < 16; ++r) o[n][r] = 0.f;
    float mrow = -1e30f, lsum = 0.f;

#pragma unroll 1
    for (int kt = 0; kt < nkt; ++kt) {
      if (kt + 1 < nkt) { WAITV8 } else { WAITV0 }
      BAR;
      if (kt + 2 < nkt) stage((kt + 2) % 3, kt + 2);

      const bf16_t* Kb = &KV[kt % 3][0][0];
      bf16x8 kf[2][4];
#pragma unroll
      for (int t = 0; t < 2; ++t)
#pragma unroll
        for (int d = 0; d < 4; ++d) {
          int row = 32 * t + l31;
          int col = ((d * 2 + hi) ^ (row & 7)) * 8;
          kf[t][d] = *(const bf16x8*)&Kb[row * 64 + col];
        }
      bf16x8 vf[2][4];
      {
        unsigned vb = lds_addr(&KV[kt % 3][1][0]);
#pragma unroll
        for (int n2 = 0; n2 < 2; ++n2)
#pragma unroll
          for (int ks = 0; ks < 4; ++ks) {
            int pn = 2 * n2 + (l31 >> 4);
            int k0 = ks * 16 + hi * 8;
            unsigned a = vb + pn * 2048 + k0 * 32 + l15 * 8;
            i32x2 lo = tr64(a);
            i32x2 hi4 = tr64o(a);
            union { unsigned u[4]; bf16x8 v; } uu;
            uu.u[0] = (unsigned)lo[0]; uu.u[1] = (unsigned)lo[1];
            uu.u[2] = (unsigned)hi4[0]; uu.u[3] = (unsigned)hi4[1];
            vf[n2][ks] = uu.v;
          }
      }
      WAITL0;

      // ---- S^T = K Q^T ----
      f32x16 st[2];
#pragma unroll
      for (int t = 0; t < 2; ++t) {
#pragma unroll
        for (int r = 0; r < 16; ++r) st[t][r] = 0.f;
#pragma unroll
        for (int d = 0; d < 4; ++d) st[t] = mfma32(kf[t][d], qf[d], st[t]);
      }
      if (kt == nkt - 1) {  // diagonal tile: causal mask
#pragma unroll
        for (int t = 0; t < 2; ++t)
#pragma unroll
          for (int r = 0; r < 16; ++r)
            if (kt * 64 + 32 * t + CROW(r) > q0 + l31) st[t][r] = -1e30f;
      }
      // ---- online softmax (exp2 domain) ----
      float pm = -1e30f;
#pragma unroll
      for (int t = 0; t < 2; ++t)
#pragma unroll
        for (int r = 0; r < 16; ++r) pm = fmaxf(pm, st[t][r]);
      pm = fmaxf(pm, __shfl_xor(pm, 32));
      if (!__all(pm - mrow <= 11.0f)) {  // defer-max
        float mn = fmaxf(mrow, pm);
        float scl = exp2f(mrow - mn);
        mrow = mn;
        lsum *= scl;
#pragma unroll
        for (int r = 0; r < 16; ++r) {
          float sr = __shfl(scl, CROW(r));
          o[0][r] *= sr;
          o[1][r] *= sr;
        }
      }
      float ps = 0.f;
#pragma unroll
      for (int t = 0; t < 2; ++t)
#pragma unroll
        for (int r = 0; r < 16; ++r) {
          float e = exp2f(st[t][r] - mrow);
          st[t][r] = e;
          ps += e;
        }
      ps += __shfl_xor(ps, 32);
      lsum += ps;
      // ---- pack P, cross-half exchange, PV ----
      unsigned pk[2][8];
#pragma unroll
      for (int t = 0; t < 2; ++t)
#pragma unroll
        for (int j = 0; j < 8; ++j) pk[t][j] = pk2(st[t][2 * j], st[t][2 * j + 1]);
#pragma unroll
      for (int ks = 0; ks < 4; ++ks) {
        const int t = ks >> 1, rb = (ks & 1) * 4;
        unsigned s0 = hi ? pk[t][rb] : pk[t][rb + 2];
        unsigned s1 = hi ? pk[t][rb + 1] : pk[t][rb + 3];
        unsigned r0 = (unsigned)__shfl_xor((int)s0, 32);
        unsigned r1 = (unsigned)__shfl_xor((int)s1, 32);
        union { unsigned u[4]; bf16x8 v; } w;
        if (hi == 0) {
          w.u[0] = pk[t][rb]; w.u[1] = pk[t][rb + 1]; w.u[2] = r0; w.u[3] = r1;
        } else {
          w.u[0] = r0; w.u[1] = r1; w.u[2] = pk[t][rb + 2]; w.u[3] = pk[t][rb + 3];
        }
        o[0] = mfma32(w.v, vf[0][ks], o[0]);
        o[1] = mfma32(w.v, vf[1][ks], o[1]);
      }
    }  // kt

    // ---- phase epilogue ----
#pragma unroll
    for (int r = 0; r < 16; ++r) {
      float li = __shfl(lsum, CROW(r));
      float inv = 1.0f / li;
      int qrow = q0 + CROW(r);
#pragma unroll
      for (int n2 = 0; n2 < 2; ++n2)
        Cg[(size_t)qrow * D_ + n2 * 32 + l31] = (bf16_t)(o[n2][r] * inv);
    }
  }  // phase
}

// ---------------- launch ----------------
extern "C" void kernel_launch(void* const* d_in, const int* in_sizes, int n_in,
                              void* d_out, int out_size, void* d_ws, size_t ws_size,
                              hipStream_t stream) {
  const float* x   = (const float*)d_in[0];
  const float* w_q = (const float*)d_in[1];
  const float* w_k = (const float*)d_in[2];
  const float* w_v = (const float*)d_in[3];
  const float* w_o = (const float*)d_in[4];

  const int M = B_ * T_;              // 4096
  const size_t XN = (size_t)M * D_;   // 4M
  const size_t WN = (size_t)D_ * D_;  // 1M

  bf16_t* ws = (bf16_t*)d_ws;
  bf16_t* xb   = ws;            // 4M
  bf16_t* wqb  = xb + XN;       // 3M (q,k,v) + 1M (o) contiguous
  bf16_t* wob  = wqb + 3 * WN;
  bf16_t* qkv  = wob + WN;      // [4096][3072] = 12M
  bf16_t* ctx  = qkv + (size_t)M * RS_;  // 4M

  cvt_x<<<(int)(XN / 4 / 256), 256, 0, stream>>>(x, xb, (int)(XN / 4));
  cvt_w4<<<dim3((int)(WN / 4 / 256), 4), 256, 0, stream>>>(w_q, w_k, w_v, w_o, wqb, (int)(WN / 4));

  // fused QKV GEMM: B = [w_q; w_k; w_v] (3072 x 1024), q-part pre-scaled (exp2 domain)
  gemm_nt<false, true><<<dim3(RS_ / 128, M / 128), 256, 0, stream>>>(xb, wqb, qkv, M, RS_, D_);

  attn_fwd<<<dim3(B_ * H_, 16), 128, 0, stream>>>(qkv, ctx);

  gemm_nt<true, false><<<dim3(D_ / 128, M / 128), 256, 0, stream>>>(ctx, wob, d_out, M, D_, D_);
}

// Round 9
// 153.545 us; speedup vs baseline: 1.0135x; 1.0135x over previous
//
#include <hip/hip_runtime.h>
#include <hip/hip_bf16.h>

typedef __bf16 bf16_t;
typedef __attribute__((ext_vector_type(8))) __bf16 bf16x8;
typedef __attribute__((ext_vector_type(4))) __bf16 bf16x4;
typedef __attribute__((ext_vector_type(4))) float f32x4;
typedef __attribute__((ext_vector_type(16))) float f32x16;
typedef __attribute__((ext_vector_type(2))) int i32x2;

#define B_ 2
#define T_ 2048
#define D_ 1024
#define H_ 16
#define DH_ 64
#define RS_ 3072  // fused qkv row stride

static __device__ __forceinline__ f32x4 mfma16(bf16x8 a, bf16x8 b, f32x4 c) {
  return __builtin_amdgcn_mfma_f32_16x16x32_bf16(a, b, c, 0, 0, 0);
}
static __device__ __forceinline__ f32x16 mfma32(bf16x8 a, bf16x8 b, f32x16 c) {
  return __builtin_amdgcn_mfma_f32_32x32x16_bf16(a, b, c, 0, 0, 0);
}
static __device__ __forceinline__ void gld16(const bf16_t* g, bf16_t* l) {
  __builtin_amdgcn_global_load_lds(
      (const __attribute__((address_space(1))) unsigned int*)g,
      (__attribute__((address_space(3))) unsigned int*)l, 16, 0, 0);
}
static __device__ __forceinline__ unsigned lds_addr(const bf16_t* p) {
  return (unsigned)(uintptr_t)(const __attribute__((address_space(3))) bf16_t*)p;
}
static __device__ __forceinline__ i32x2 tr64(unsigned a) {
  i32x2 d;
  asm volatile("ds_read_b64_tr_b16 %0, %1" : "=v"(d) : "v"(a));
  return d;
}
static __device__ __forceinline__ i32x2 tr64o(unsigned a) {  // +128B (4 k-rows)
  i32x2 d;
  asm volatile("ds_read_b64_tr_b16 %0, %1 offset:128" : "=v"(d) : "v"(a));
  return d;
}
static __device__ __forceinline__ unsigned pk2(float lo, float hi2) {
  unsigned short a = __builtin_bit_cast(unsigned short, (bf16_t)lo);
  unsigned short b = __builtin_bit_cast(unsigned short, (bf16_t)hi2);
  return (unsigned)a | ((unsigned)b << 16);
}

#define WAITV4 { asm volatile("s_waitcnt vmcnt(4)" ::: "memory"); __builtin_amdgcn_sched_barrier(0); }
#define WAITV8 { asm volatile("s_waitcnt vmcnt(8)" ::: "memory"); __builtin_amdgcn_sched_barrier(0); }
#define WAITV0 { asm volatile("s_waitcnt vmcnt(0)" ::: "memory"); __builtin_amdgcn_sched_barrier(0); }
#define BAR    { __builtin_amdgcn_s_barrier(); __builtin_amdgcn_sched_barrier(0); }
#define WAITL0 { asm volatile("s_waitcnt lgkmcnt(0)" ::: "memory"); __builtin_amdgcn_sched_barrier(0); }

// ---------------- fp32 -> bf16 conversion ----------------
__global__ __launch_bounds__(256) void cvt_x(const float* __restrict__ in,
                                             bf16_t* __restrict__ out, int n4) {
  int i = blockIdx.x * 256 + threadIdx.x;
  if (i >= n4) return;
  float4 f = reinterpret_cast<const float4*>(in)[i];
  bf16x4 o;
  o[0] = (bf16_t)f.x; o[1] = (bf16_t)f.y; o[2] = (bf16_t)f.z; o[3] = (bf16_t)f.w;
  reinterpret_cast<bf16x4*>(out)[i] = o;
}

__global__ __launch_bounds__(256) void cvt_w4(const float* __restrict__ w0,
                                              const float* __restrict__ w1,
                                              const float* __restrict__ w2,
                                              const float* __restrict__ w3,
                                              bf16_t* __restrict__ out, int n4each) {
  const float* in = blockIdx.y == 0 ? w0 : blockIdx.y == 1 ? w1 : blockIdx.y == 2 ? w2 : w3;
  bf16_t* o = out + (size_t)blockIdx.y * (size_t)n4each * 4;
  int i = blockIdx.x * 256 + threadIdx.x;
  if (i >= n4each) return;
  float4 f = reinterpret_cast<const float4*>(in)[i];
  bf16x4 v;
  v[0] = (bf16_t)f.x; v[1] = (bf16_t)f.y; v[2] = (bf16_t)f.z; v[3] = (bf16_t)f.w;
  reinterpret_cast<bf16x4*>(o)[i] = v;
}

// ---------------- NT GEMM: C = A * B^T (unchanged from R7) ----------------
template <bool STORE_F32, bool QSCALE>
__global__ __launch_bounds__(256) void gemm_nt(const bf16_t* __restrict__ A,
                                               const bf16_t* __restrict__ Bm,
                                               void* __restrict__ Cv,
                                               int M, int N, int K) {
  __shared__ __align__(16) bf16_t As[3][128 * 32];
  __shared__ __align__(16) bf16_t Bs[3][128 * 32];
  const int tid = threadIdx.x, lane = tid & 63, wave = tid >> 6;
  const int l15 = lane & 15;
  const int brow = blockIdx.y * 128, bcol = blockIdx.x * 128;
  const int row0 = (wave >> 1) * 64, col0 = (wave & 1) * 64;
  const float cscale = (QSCALE && bcol < 1024) ? 0.18033688011112042f : 1.0f;

  f32x4 acc[4][4];
#pragma unroll
  for (int m = 0; m < 4; ++m)
#pragma unroll
    for (int n = 0; n < 4; ++n) acc[m][n] = f32x4{0.f, 0.f, 0.f, 0.f};

  const int nst = K >> 5;
  const int srow = tid >> 2;
  const int sc8 = (tid & 3) * 8;
  auto stage = [&](int bi, int ks) {
    const int k0 = ks * 32;
#pragma unroll
    for (int i = 0; i < 2; ++i)
      gld16(A + (size_t)(brow + 64 * i + srow) * K + k0 + sc8,
            &As[bi][2048 * i + 512 * wave]);
#pragma unroll
    for (int i = 0; i < 2; ++i)
      gld16(Bm + (size_t)(bcol + 64 * i + srow) * K + k0 + sc8,
            &Bs[bi][2048 * i + 512 * wave]);
  };

  stage(0, 0);
  stage(1, 1);

#pragma unroll 1
  for (int ks = 0; ks < nst; ++ks) {
    if (ks + 1 < nst) { WAITV4 } else { WAITV0 }
    BAR;
    if (ks + 2 < nst) stage((ks + 2) % 3, ks + 2);

    const bf16_t* Ab = &As[ks % 3][0];
    const bf16_t* Bb = &Bs[ks % 3][0];
    const int ko = (lane >> 4) * 8;
    bf16x8 af[4], bfr[4];
#pragma unroll
    for (int m = 0; m < 4; ++m)
      af[m] = *(const bf16x8*)&Ab[(row0 + 16 * m + l15) * 32 + ko];
#pragma unroll
    for (int n = 0; n < 4; ++n)
      bfr[n] = *(const bf16x8*)&Bb[(col0 + 16 * n + l15) * 32 + ko];
    WAITL0;
#pragma unroll
    for (int m = 0; m < 4; ++m)
#pragma unroll
      for (int n = 0; n < 4; ++n) acc[m][n] = mfma16(af[m], bfr[n], acc[m][n]);
  }

  const int crow = brow + row0 + (lane >> 4) * 4;
  const int ccol = bcol + col0 + l15;
#pragma unroll
  for (int m = 0; m < 4; ++m)
#pragma unroll
    for (int n = 0; n < 4; ++n)
#pragma unroll
      for (int r = 0; r < 4; ++r) {
        size_t idx = (size_t)(crow + 16 * m + r) * N + (ccol + 16 * n);
        float v = acc[m][n][r] * cscale;
        if (STORE_F32) reinterpret_cast<float*>(Cv)[idx] = v;
        else reinterpret_cast<bf16_t*>(Cv)[idx] = (bf16_t)v;
      }
}

// ---------------- causal flash attention ----------------
// 512 blocks x 4 INDEPENDENT waves (no barriers). Per-wave private K/V staging,
// KVBLK=32, double-buffered, counted vmcnt(8) (stage(kt+1) issued before wait).
// LDS/block 64KB -> 2 blocks/CU = 8 waves/CU = 2 waves/SIMD.
// Chunk map: y<8: wave w -> even chunk 8y+2w (nkt=8y+2w+1);
//            y>=8: odd chunk 63-8(y-8)-2w (nkt=64-8(y-8)-2w).
// CU hosts blocks (y, y+8); SIMD s gets one wave of each: nkt sum = 65 = constant.
#define CROW(r) ((((r) & 3) + 8 * ((r) >> 2)) + 4 * hi)

__global__ __launch_bounds__(256, 2) void attn_fwd(const bf16_t* __restrict__ qkv,
                                                   bf16_t* __restrict__ ctx) {
  __shared__ __align__(128) bf16_t KV[4][2][2][2048];  // [wave][buf][K|V][2048] = 64KB
  const int lane = threadIdx.x & 63;
  const int wv = threadIdx.x >> 6;
  const int bh = blockIdx.x, y = blockIdx.y;
  const int b = bh >> 4, h = bh & 15;
  const int c = (y < 8) ? (8 * y + 2 * wv) : (63 - 8 * (y - 8) - 2 * wv);
  const int q0 = c * 32;
  const int nkt = c + 1;  // 32-key tiles
  const bf16_t* Qg = qkv + (size_t)b * T_ * RS_ + h * DH_;
  const bf16_t* Kg = Qg + 1024;
  const bf16_t* Vg = Qg + 2048;
  bf16_t* Cg = ctx + (size_t)b * T_ * D_ + h * DH_;

  const int hi = lane >> 5;
  const int l31 = lane & 31;
  const int l15 = lane & 15;

  bf16_t* Kb[2] = {&KV[wv][0][0][0], &KV[wv][1][0][0]};
  bf16_t* Vb[2] = {&KV[wv][0][1][0], &KV[wv][1][1][0]};

  // per-wave staging of one 32-key tile: 4KB K (swizzled rows) + 4KB V (16-wide panels)
  auto stage = [&](int bi, int kt) {
#pragma unroll
    for (int i = 0; i < 4; ++i) {
      int c2 = i * 64 + lane;
      int r = c2 >> 3, g8 = (c2 & 7) ^ (r & 7);
      gld16(Kg + (size_t)(kt * 32 + r) * RS_ + g8 * 8, Kb[bi] + i * 512);
    }
#pragma unroll
    for (int i = 0; i < 4; ++i) {
      int pn = i, k = lane >> 1, half = lane & 1;
      gld16(Vg + (size_t)(kt * 32 + k) * RS_ + pn * 16 + half * 8, Vb[bi] + i * 512);
    }
  };

  // Q fragments (exp2-domain pre-scaled), regs for whole kernel
  bf16x8 qf[4];
#pragma unroll
  for (int d = 0; d < 4; ++d)
    qf[d] = *(const bf16x8*)&Qg[(size_t)(q0 + l31) * RS_ + d * 16 + hi * 8];

  f32x16 o[2];
#pragma unroll
  for (int n = 0; n < 2; ++n)
#pragma unroll
    for (int r = 0; r < 16; ++r) o[n][r] = 0.f;
  float mrow = -1e30f, lsum = 0.f;

  stage(0, 0);
  int cur = 0;

#pragma unroll 1
  for (int kt = 0; kt < nkt; ++kt) {
    if (kt + 1 < nkt) {
      stage(cur ^ 1, kt + 1);  // issue next tile FIRST, then counted wait
      WAITV8;                  // drains stage(kt), leaves stage(kt+1) in flight
    } else {
      WAITV0;
    }

    // ---- K fragments (32 rows) ----
    bf16x8 kf[4];
#pragma unroll
    for (int d = 0; d < 4; ++d) {
      int col = ((d * 2 + hi) ^ (l31 & 7)) * 8;
      kf[d] = *(const bf16x8*)&Kb[cur][l31 * 64 + col];
    }
    // ---- V fragments via transpose-read (panels [4][32][16]) ----
    bf16x8 vf[2][2];
    {
      unsigned vb = lds_addr(Vb[cur]);
#pragma unroll
      for (int n2 = 0; n2 < 2; ++n2)
#pragma unroll
        for (int ks = 0; ks < 2; ++ks) {
          int pn = 2 * n2 + (l31 >> 4);
          int k0 = ks * 16 + hi * 8;
          unsigned a = vb + pn * 1024 + k0 * 32 + l15 * 8;
          i32x2 lo = tr64(a);
          i32x2 hi4 = tr64o(a);
          union { unsigned u[4]; bf16x8 v; } uu;
          uu.u[0] = (unsigned)lo[0]; uu.u[1] = (unsigned)lo[1];
          uu.u[2] = (unsigned)hi4[0]; uu.u[3] = (unsigned)hi4[1];
          vf[n2][ks] = uu.v;
        }
    }
    WAITL0;

    // ---- S^T = K Q^T (32k x 32q) ----
    f32x16 st;
#pragma unroll
    for (int r = 0; r < 16; ++r) st[r] = 0.f;
#pragma unroll
    for (int d = 0; d < 4; ++d) st = mfma32(kf[d], qf[d], st);
    if (kt == nkt - 1) {  // diagonal tile: causal mask
#pragma unroll
      for (int r = 0; r < 16; ++r)
        if (CROW(r) > l31) st[r] = -1e30f;
    }
    // ---- online softmax (exp2 domain) ----
    float pm = -1e30f;
#pragma unroll
    for (int r = 0; r < 16; ++r) pm = fmaxf(pm, st[r]);
    pm = fmaxf(pm, __shfl_xor(pm, 32));
    if (!__all(pm - mrow <= 11.0f)) {  // defer-max
      float mn = fmaxf(mrow, pm);
      float scl = exp2f(mrow - mn);
      mrow = mn;
      lsum *= scl;
#pragma unroll
      for (int r = 0; r < 16; ++r) {
        float sr = __shfl(scl, CROW(r));
        o[0][r] *= sr;
        o[1][r] *= sr;
      }
    }
    float ps = 0.f;
#pragma unroll
    for (int r = 0; r < 16; ++r) {
      float e = exp2f(st[r] - mrow);
      st[r] = e;
      ps += e;
    }
    ps += __shfl_xor(ps, 32);
    lsum += ps;
    // ---- pack P, cross-half exchange, PV ----
    unsigned pk[8];
#pragma unroll
    for (int j = 0; j < 8; ++j) pk[j] = pk2(st[2 * j], st[2 * j + 1]);
#pragma unroll
    for (int ks = 0; ks < 2; ++ks) {
      const int rb = ks * 4;
      unsigned s0 = hi ? pk[rb] : pk[rb + 2];
      unsigned s1 = hi ? pk[rb + 1] : pk[rb + 3];
      unsigned r0 = (unsigned)__shfl_xor((int)s0, 32);
      unsigned r1 = (unsigned)__shfl_xor((int)s1, 32);
      union { unsigned u[4]; bf16x8 v; } w;
      if (hi == 0) {
        w.u[0] = pk[rb]; w.u[1] = pk[rb + 1]; w.u[2] = r0; w.u[3] = r1;
      } else {
        w.u[0] = r0; w.u[1] = r1; w.u[2] = pk[rb + 2]; w.u[3] = pk[rb + 3];
      }
      o[0] = mfma32(w.v, vf[0][ks], o[0]);
      o[1] = mfma32(w.v, vf[1][ks], o[1]);
    }
    cur ^= 1;
  }  // kt

  // ---- epilogue ----
#pragma unroll
  for (int r = 0; r < 16; ++r) {
    float li = __shfl(lsum, CROW(r));
    float inv = 1.0f / li;
    int qrow = q0 + CROW(r);
#pragma unroll
    for (int n2 = 0; n2 < 2; ++n2)
      Cg[(size_t)qrow * D_ + n2 * 32 + l31] = (bf16_t)(o[n2][r] * inv);
  }
}

// ---------------- launch ----------------
extern "C" void kernel_launch(void* const* d_in, const int* in_sizes, int n_in,
                              void* d_out, int out_size, void* d_ws, size_t ws_size,
                              hipStream_t stream) {
  const float* x   = (const float*)d_in[0];
  const float* w_q = (const float*)d_in[1];
  const float* w_k = (const float*)d_in[2];
  const float* w_v = (const float*)d_in[3];
  const float* w_o = (const float*)d_in[4];

  const int M = B_ * T_;              // 4096
  const size_t XN = (size_t)M * D_;   // 4M
  const size_t WN = (size_t)D_ * D_;  // 1M

  bf16_t* ws = (bf16_t*)d_ws;
  bf16_t* xb   = ws;            // 4M
  bf16_t* wqb  = xb + XN;       // 3M (q,k,v) + 1M (o) contiguous
  bf16_t* wob  = wqb + 3 * WN;
  bf16_t* qkv  = wob + WN;      // [4096][3072] = 12M
  bf16_t* ctx  = qkv + (size_t)M * RS_;  // 4M

  cvt_x<<<(int)(XN / 4 / 256), 256, 0, stream>>>(x, xb, (int)(XN / 4));
  cvt_w4<<<dim3((int)(WN / 4 / 256), 4), 256, 0, stream>>>(w_q, w_k, w_v, w_o, wqb, (int)(WN / 4));

  // fused QKV GEMM: B = [w_q; w_k; w_v] (3072 x 1024), q-part pre-scaled (exp2 domain)
  gemm_nt<false, true><<<dim3(RS_ / 128, M / 128), 256, 0, stream>>>(xb, wqb, qkv, M, RS_, D_);

  attn_fwd<<<dim3(B_ * H_, 16), 256, 0, stream>>>(qkv, ctx);

  gemm_nt<true, false><<<dim3(D_ / 128, M / 128), 256, 0, stream>>>(ctx, wob, d_out, M, D_, D_);
}